// Round 9
// baseline (526.358 us; speedup 1.0000x reference)
//
#include <hip/hip_runtime.h>
#include <hip/hip_bf16.h>
#include <math.h>

// ---- problem constants ----
#define T_TOK  4096      // B*S tokens
#define H_DIM  1024
#define E_NUM  8
#define FF_DIM 4096
#define KSEL   2
#define SLOTS  (T_TOK*KSEL)     // 8192
#define SLOTS_PAD (SLOTS + 256)
#define MAXT256  40             // 256-row tiles (max sum of per-expert ceils)

typedef __attribute__((ext_vector_type(8))) short s16x8;
typedef __attribute__((ext_vector_type(8))) unsigned short u16x8;
typedef __attribute__((ext_vector_type(4))) float f32x4;

typedef __attribute__((address_space(1))) const void global_cvoid;
typedef __attribute__((address_space(3))) void lds_void;

__device__ __forceinline__ unsigned short f2bf(float f){
  unsigned int u = __float_as_uint(f);
  u += 0x7fffu + ((u>>16)&1u);
  return (unsigned short)(u>>16);
}
__device__ __forceinline__ float bf2f(unsigned short h){
  return __uint_as_float(((unsigned int)h)<<16);
}

// ---- workspace layout ----
static constexpr size_t OFF_CNT   = 0;
static constexpr size_t OFF_OFFS  = 256;
static constexpr size_t OFF_NT256 = 512;
static constexpr size_t OFF_T256  = 768;
static constexpr size_t OFF_IDX   = 1280;
static constexpr size_t OFF_POS   = OFF_IDX  + 32768;
static constexpr size_t OFF_WV    = OFF_POS  + 32768;
static constexpr size_t OFF_SLOT  = OFF_WV   + 32768;
static constexpr size_t OFF_TOK   = OFF_SLOT + 32768;
static constexpr size_t OFF_WOF   = OFF_TOK  + 32768;
static constexpr size_t OFF_XG    = OFF_WOF  + 32768;                       // [SLOTS_PAD][H] bf16
static constexpr size_t OFF_W1T   = OFF_XG  + (size_t)SLOTS_PAD*H_DIM*2;    // [E][FF][H] bf16
static constexpr size_t OFF_W2T   = OFF_W1T + (size_t)E_NUM*H_DIM*FF_DIM*2; // [E][H][FF] bf16
static constexpr size_t OFF_MID   = OFF_W2T + (size_t)E_NUM*H_DIM*FF_DIM*2; // [SLOTS_PAD][FF] bf16
static constexpr size_t OFF_Y     = OFF_MID + (size_t)SLOTS_PAD*FF_DIM*2;   // [SLOTS][H] bf16

// ---- gating ----
__global__ __launch_bounds__(64) void gate_kernel(
    const float* __restrict__ x, const float* __restrict__ Wg,
    const float* __restrict__ bg, int* __restrict__ cnt,
    int* __restrict__ idxp, int* __restrict__ posp, float* __restrict__ wvp)
{
  int t = blockIdx.x, lane = threadIdx.x;
  const float* xr = x + (size_t)t*H_DIM;
  float acc[E_NUM];
  #pragma unroll
  for (int e=0;e<E_NUM;e++) acc[e]=0.f;
  for (int i=0;i<H_DIM/64;i++){
    int h = i*64 + lane;
    float xv = xr[h];
    const float* wr_ = Wg + (size_t)h*E_NUM;
    #pragma unroll
    for (int e=0;e<E_NUM;e++) acc[e] += xv*wr_[e];
  }
  #pragma unroll
  for (int e=0;e<E_NUM;e++){
    #pragma unroll
    for (int off=32; off>0; off>>=1) acc[e] += __shfl_xor(acc[e], off);
  }
  if (lane==0){
    float l[E_NUM];
    #pragma unroll
    for (int e=0;e<E_NUM;e++) l[e] = acc[e] + bg[e];
    int i0 = 0;
    #pragma unroll
    for (int e=1;e<E_NUM;e++) if (l[e] > l[i0]) i0 = e;
    int i1 = (i0==0)?1:0;
    #pragma unroll
    for (int e=0;e<E_NUM;e++) if (e!=i0 && l[e] > l[i1]) i1 = e;
    float p1 = expf(l[i1]-l[i0]);
    float s  = 1.f + p1;
    float w0 = 1.f/s, w1 = p1/s;
    int pos0 = atomicAdd(&cnt[i0],1);
    int pos1 = atomicAdd(&cnt[i1],1);
    idxp[t*2]=i0; idxp[t*2+1]=i1;
    posp[t*2]=pos0; posp[t*2+1]=pos1;
    wvp[t*2]=w0; wvp[t*2+1]=w1;
  }
}

// ---- plan: prefix sums + 256-row tile worklist ----
__global__ void plan_kernel(const int* __restrict__ cnt, int* __restrict__ offs,
                            int* __restrict__ tiles256, int* __restrict__ ntiles256)
{
  int o=0, n2=0;
  for (int e=0;e<E_NUM;e++){
    offs[e]=o;
    int c=cnt[e];
    int nt2=(c+255)/256;
    for (int m=0;m<nt2;m++) tiles256[n2++] = (e<<16)|m;
    o+=c;
  }
  offs[E_NUM]=o;
  *ntiles256=n2;
}

// ---- scatter ----
__global__ void scatter_kernel(const int* __restrict__ idxp, const int* __restrict__ posp,
                               const float* __restrict__ wvp, const int* __restrict__ offs,
                               int* __restrict__ tok_of, float* __restrict__ w_of,
                               int* __restrict__ slot_of)
{
  int i = blockIdx.x*blockDim.x + threadIdx.x;
  if (i >= SLOTS) return;
  int t = i>>1, k = i&1;
  int e = idxp[t*2+k];
  int slot = offs[e] + posp[t*2+k];
  tok_of[slot] = t;
  w_of[slot]   = wvp[t*2+k];
  slot_of[t*2+k] = slot;
}

// ---- gather ----
__global__ __launch_bounds__(256) void gather_kernel(
    const float* __restrict__ x, const int* __restrict__ tok_of,
    unsigned short* __restrict__ Xg)
{
  int slot = blockIdx.x;
  int t = tok_of[slot];
  const float4* src = (const float4*)(x + (size_t)t*H_DIM);
  float4 v = src[threadIdx.x];
  ushort4 o;
  o.x=f2bf(v.x); o.y=f2bf(v.y); o.z=f2bf(v.z); o.w=f2bf(v.w);
  ((ushort4*)(Xg + (size_t)slot*H_DIM))[threadIdx.x] = o;
}

// ---- transpose + convert ----
__global__ __launch_bounds__(256) void transconv_kernel(
    const float* __restrict__ in, unsigned short* __restrict__ out, int R, int C)
{
  __shared__ float tile[64][65];
  int e = blockIdx.z;
  const float* inp = in + (size_t)e*R*C;
  unsigned short* op = out + (size_t)e*R*C;
  int c0 = blockIdx.x*64, r0 = blockIdx.y*64;
  int tx = threadIdx.x & 15, ty = threadIdx.x >> 4;
  #pragma unroll
  for (int i=0;i<4;i++){
    int r = i*16 + ty;
    float4 v = *(const float4*)(inp + (size_t)(r0+r)*C + c0 + tx*4);
    tile[r][tx*4+0]=v.x; tile[r][tx*4+1]=v.y; tile[r][tx*4+2]=v.z; tile[r][tx*4+3]=v.w;
  }
  __syncthreads();
  int wx = threadIdx.x & 7;
  int wcl = threadIdx.x >> 3;
  #pragma unroll
  for (int i=0;i<2;i++){
    int c = i*32 + wcl;
    u16x8 o;
    #pragma unroll
    for (int j=0;j<8;j++) o[j] = f2bf(tile[wx*8+j][c]);
    *(u16x8*)(op + (size_t)(c0+c)*R + r0 + wx*8) = o;
  }
}

#define GLDS(g, l) __builtin_amdgcn_global_load_lds((global_cvoid*)(g), (lds_void*)(l), 16, 0, 0)
#define VMW(n) asm volatile("s_waitcnt vmcnt(" #n ")" ::: "memory")
#define FENCE asm volatile("" ::: "memory")

// ==== grouped GEMM: 256xBN tile, BK=64, 512 thr (8 waves 2Mx4N), true 8-phase
// region-granular schedule (4 phases/K-tile x 2 K-tiles in flight):
//  regions {A,B}x{ks0,ks1}; stage slot = one phase after region's last reader;
//  issue stream: ph0->A_ks1(kt+1), ph1->B_ks0(kt+2), ph2->A_ks0(kt+2),
//  ph3->B_ks1(kt+2); counted vmcnt only at end-ph1/ph3 (steady 3LB+2LA),
//  exact tail waits. Swizzle: phys chunk=(fq+(row>>1))&3 (2-way = free).
// MODE 0: gelu epilogue. MODE 1: gate-scale epilogue. ====
template<int MODE, int BN>
__global__ __launch_bounds__(512, 2) void gemm256p8_kernel(
    const unsigned short* __restrict__ A,    // [rows][K]
    const unsigned short* __restrict__ Bt,   // [E][N][K]
    const float* __restrict__ bias,          // [E][N]
    unsigned short* __restrict__ Out,        // [rows][N]
    const int* __restrict__ tiles256, const int* __restrict__ ntiles256,
    const int* __restrict__ cnt, const int* __restrict__ offs,
    const float* __restrict__ w_of,
    int N, int K, int cshift)
{
  constexpr int NFR = BN/64;          // B frags per wave (4 or 2)
  constexpr int LB  = (BN==256)?2:1;  // gloads per B region
  constexpr int ARB = 16384;          // A region bytes (256 rows x 64B)
  constexpr int ABUF = 2*ARB;
  constexpr int BRB = BN*64;          // B region bytes
  constexpr int BBUF = 2*BRB;

  int tile_id = blockIdx.x >> cshift;
  if (tile_id >= *ntiles256) return;
  int col0 = (blockIdx.x & ((1<<cshift)-1)) * BN;
  int packed = tiles256[tile_id];
  int e = packed>>16, mt = packed & 0xffff;
  int row0 = offs[e] + mt*256;
  int nvalid = cnt[e] - mt*256; if (nvalid > 256) nvalid = 256;
  const unsigned short* Be = Bt + (size_t)e*N*K;

  __shared__ char asmem[2*ABUF];      // 64 KB
  __shared__ char bsmem[2*BBUF];      // 64 or 32 KB

  int t = threadIdx.x;
  int wid = t>>6, lane = t&63;
  int wm = wid>>2, wn = wid&3;
  int fr = lane&15, fq = lane>>4;

  // ---- staging geometry: thread t -> row t>>2 of a 128-row half, phys chunk t&3.
  // stored logical chunk c_l = (c_phys - (row>>1)) & 3  (inverse of read swizzle)
  int srow = t>>2;
  int scl  = ((t&3) - ((t>>3)&3)) & 3;
  int sdst = wid*1024;                // wave-uniform LDS base within 8KB half
  const unsigned short* pA0 = A  + (size_t)(row0 + srow)*K + scl*8;
  const unsigned short* pA1 = A  + (size_t)(row0 + 128 + srow)*K + scl*8;
  const unsigned short* pB0 = Be + (size_t)(col0 + srow)*K + scl*8;
  const unsigned short* pB1 = Be + (size_t)(col0 + ((LB==2)?128:0) + srow)*K + scl*8;

  // ---- read addressing: row = base16 + fr -> (row>>1)&3 == (fr>>1)&3
  int rdc   = ((fq + ((fr>>1)&3)) & 3) << 4;
  int aBase = wm*8192 + fr*64 + rdc;
  int bBase = wn*(BN/4)*64 + fr*64 + rdc;

  auto stageA = [&](int buf, int ks, int kt){
    GLDS(pA0 + kt*64 + ks*32, asmem + buf*ABUF + ks*ARB + sdst);
    GLDS(pA1 + kt*64 + ks*32, asmem + buf*ABUF + ks*ARB + 8192 + sdst);
  };
  auto stageB = [&](int buf, int ks, int kt){
    GLDS(pB0 + kt*64 + ks*32, bsmem + buf*BBUF + ks*BRB + sdst);
    if constexpr (LB==2)
      GLDS(pB1 + kt*64 + ks*32, bsmem + buf*BBUF + ks*BRB + 8192 + sdst);
  };

  f32x4 acc[8][NFR];
  #pragma unroll
  for (int i=0;i<8;i++)
    #pragma unroll
    for (int n=0;n<NFR;n++) acc[i][n] = (f32x4){0.f,0.f,0.f,0.f};
  s16x8 bfr[NFR];

  int NT = K >> 6;                    // 16 (G1) / 64 (G2)

  // ---- prologue: B0(0) A0(0) B1(0) A1(0) B0(1) A0(1) B1(1); A1(1) comes at ph0(0)
  stageB(0,0,0); stageA(0,0,0); stageB(0,1,0); stageA(0,1,0);
  stageB(1,0,1); stageA(1,0,1); stageB(1,1,1);
  if constexpr (LB==2) VMW(10); else VMW(7);
  __builtin_amdgcn_s_barrier(); FENCE;

  for (int kt=0; kt<NT; ++kt){
    int cur = kt&1, nxt = cur^1;
    const char* aB = asmem + cur*ABUF;
    const char* bB = bsmem + cur*BBUF;

    // ---------- ph0: ks0, m0-3 ; stage A_ks1(kt+1) -> nxt ----------
    {
      #pragma unroll
      for (int n=0;n<NFR;n++) bfr[n] = *(const s16x8*)(bB + n*1024 + bBase);
      s16x8 af[4];
      #pragma unroll
      for (int i=0;i<4;i++) af[i] = *(const s16x8*)(aB + i*1024 + aBase);
      if (kt+1 < NT) stageA(nxt, 1, kt+1);
      __builtin_amdgcn_s_barrier(); FENCE;
      asm volatile("s_waitcnt lgkmcnt(0)" ::: "memory");
      __builtin_amdgcn_sched_barrier(0);
      __builtin_amdgcn_s_setprio(1);
      #pragma unroll
      for (int i=0;i<4;i++)
        #pragma unroll
        for (int n=0;n<NFR;n++)
          acc[i][n] = __builtin_amdgcn_mfma_f32_16x16x32_bf16(af[i], bfr[n], acc[i][n], 0,0,0);
      __builtin_amdgcn_s_setprio(0);
      __builtin_amdgcn_s_barrier(); FENCE;
    }
    // ---------- ph1: ks0, m4-7 ; stage B_ks0(kt+2) -> cur ; wait ----------
    {
      s16x8 af[4];
      #pragma unroll
      for (int i=0;i<4;i++) af[i] = *(const s16x8*)(aB + (4+i)*1024 + aBase);
      if (kt+2 < NT) stageB(cur, 0, kt+2);
      __builtin_amdgcn_s_barrier(); FENCE;
      asm volatile("s_waitcnt lgkmcnt(0)" ::: "memory");
      __builtin_amdgcn_sched_barrier(0);
      __builtin_amdgcn_s_setprio(1);
      #pragma unroll
      for (int i=0;i<4;i++)
        #pragma unroll
        for (int n=0;n<NFR;n++)
          acc[4+i][n] = __builtin_amdgcn_mfma_f32_16x16x32_bf16(af[i], bfr[n], acc[4+i][n], 0,0,0);
      __builtin_amdgcn_s_setprio(0);
      // certify B_ks1(kt), A_ks1(kt) for ph2/ph3 reads
      if (kt < NT-2)      { if constexpr (LB==2) VMW(10); else VMW(7); }
      else if (kt == NT-2){ if constexpr (LB==2) VMW(8);  else VMW(6); }
      else                { VMW(0); }
      __builtin_amdgcn_s_barrier(); FENCE;
    }
    // ---------- ph2: ks1, m0-3 ; stage A_ks0(kt+2) -> cur ----------
    {
      #pragma unroll
      for (int n=0;n<NFR;n++) bfr[n] = *(const s16x8*)(bB + BRB + n*1024 + bBase);
      s16x8 af[4];
      #pragma unroll
      for (int i=0;i<4;i++) af[i] = *(const s16x8*)(aB + ARB + i*1024 + aBase);
      if (kt+2 < NT) stageA(cur, 0, kt+2);
      __builtin_amdgcn_s_barrier(); FENCE;
      asm volatile("s_waitcnt lgkmcnt(0)" ::: "memory");
      __builtin_amdgcn_sched_barrier(0);
      __builtin_amdgcn_s_setprio(1);
      #pragma unroll
      for (int i=0;i<4;i++)
        #pragma unroll
        for (int n=0;n<NFR;n++)
          acc[i][n] = __builtin_amdgcn_mfma_f32_16x16x32_bf16(af[i], bfr[n], acc[i][n], 0,0,0);
      __builtin_amdgcn_s_setprio(0);
      __builtin_amdgcn_s_barrier(); FENCE;
    }
    // ---------- ph3: ks1, m4-7 ; stage B_ks1(kt+2) -> cur ; wait ----------
    {
      s16x8 af[4];
      #pragma unroll
      for (int i=0;i<4;i++) af[i] = *(const s16x8*)(aB + ARB + (4+i)*1024 + aBase);
      if (kt+2 < NT) stageB(cur, 1, kt+2);
      __builtin_amdgcn_s_barrier(); FENCE;
      asm volatile("s_waitcnt lgkmcnt(0)" ::: "memory");
      __builtin_amdgcn_sched_barrier(0);
      __builtin_amdgcn_s_setprio(1);
      #pragma unroll
      for (int i=0;i<4;i++)
        #pragma unroll
        for (int n=0;n<NFR;n++)
          acc[4+i][n] = __builtin_amdgcn_mfma_f32_16x16x32_bf16(af[i], bfr[n], acc[4+i][n], 0,0,0);
      __builtin_amdgcn_s_setprio(0);
      // certify B_ks0(kt+1), A_ks0(kt+1) for next ph0 reads
      if (kt < NT-2)      { if constexpr (LB==2) VMW(10); else VMW(7); }
      else if (kt == NT-2){ if constexpr (LB==2) VMW(4);  else VMW(3); }
      __builtin_amdgcn_s_barrier(); FENCE;
    }
  }

  // ---- epilogue ----
  float bias_v[NFR];
  #pragma unroll
  for (int n=0;n<NFR;n++) bias_v[n] = bias[(size_t)e*N + col0 + wn*(BN/4) + n*16 + fr];
  #pragma unroll
  for (int m=0;m<8;m++){
    #pragma unroll
    for (int r=0;r<4;r++){
      int lrow = wm*128 + m*16 + fq*4 + r;
      if (lrow < nvalid){
        int grow = row0 + lrow;
        float scale = (MODE==1) ? w_of[grow] : 0.f;
        #pragma unroll
        for (int n=0;n<NFR;n++){
          int col = col0 + wn*(BN/4) + n*16 + fr;
          float v = acc[m][n][r] + bias_v[n];
          if (MODE==0) v = 0.5f*v*(1.f + erff(v*0.70710678118654752f));
          else         v *= scale;
          Out[(size_t)grow*N + col] = f2bf(v);
        }
      }
    }
  }
}

// ---- combine ----
__global__ __launch_bounds__(256) void combine_kernel(
    const unsigned short* __restrict__ y, const int* __restrict__ slot_of,
    float* __restrict__ out)
{
  int tok = blockIdx.x;
  int s0 = slot_of[tok*2], s1 = slot_of[tok*2+1];
  const ushort4* y0 = (const ushort4*)(y + (size_t)s0*H_DIM);
  const ushort4* y1 = (const ushort4*)(y + (size_t)s1*H_DIM);
  float4* o = (float4*)(out + (size_t)tok*H_DIM);
  ushort4 a = y0[threadIdx.x], b = y1[threadIdx.x];
  float4 r;
  r.x = bf2f(a.x)+bf2f(b.x);
  r.y = bf2f(a.y)+bf2f(b.y);
  r.z = bf2f(a.z)+bf2f(b.z);
  r.w = bf2f(a.w)+bf2f(b.w);
  o[threadIdx.x] = r;
}

extern "C" void kernel_launch(void* const* d_in, const int* in_sizes, int n_in,
                              void* d_out, int out_size, void* d_ws, size_t ws_size,
                              hipStream_t stream) {
  const float* x  = (const float*)d_in[0];
  const float* Wg = (const float*)d_in[1];
  const float* bg = (const float*)d_in[2];
  const float* W1 = (const float*)d_in[3];
  const float* b1 = (const float*)d_in[4];
  const float* W2 = (const float*)d_in[5];
  const float* b2 = (const float*)d_in[6];
  float* out = (float*)d_out;
  char* ws = (char*)d_ws;

  int*   cnt      = (int*)  (ws + OFF_CNT);
  int*   offs     = (int*)  (ws + OFF_OFFS);
  int*   ntiles256= (int*)  (ws + OFF_NT256);
  int*   tiles256 = (int*)  (ws + OFF_T256);
  int*   idxp     = (int*)  (ws + OFF_IDX);
  int*   posp     = (int*)  (ws + OFF_POS);
  float* wvp      = (float*)(ws + OFF_WV);
  int*   slot_of  = (int*)  (ws + OFF_SLOT);
  int*   tok_of   = (int*)  (ws + OFF_TOK);
  float* w_of     = (float*)(ws + OFF_WOF);
  unsigned short* Xg  = (unsigned short*)(ws + OFF_XG);
  unsigned short* W1t = (unsigned short*)(ws + OFF_W1T);
  unsigned short* W2t = (unsigned short*)(ws + OFF_W2T);
  unsigned short* mid = (unsigned short*)(ws + OFF_MID);
  unsigned short* y   = (unsigned short*)(ws + OFF_Y);

  hipMemsetAsync(ws + OFF_CNT, 0, 32, stream);

  gate_kernel<<<T_TOK, 64, 0, stream>>>(x, Wg, bg, cnt, idxp, posp, wvp);
  plan_kernel<<<1, 1, 0, stream>>>(cnt, offs, tiles256, ntiles256);
  scatter_kernel<<<SLOTS/256, 256, 0, stream>>>(idxp, posp, wvp, offs, tok_of, w_of, slot_of);
  gather_kernel<<<SLOTS, 256, 0, stream>>>(x, tok_of, Xg);

  transconv_kernel<<<dim3(FF_DIM/64, H_DIM/64, E_NUM), 256, 0, stream>>>(W1, W1t, H_DIM, FF_DIM);
  transconv_kernel<<<dim3(H_DIM/64, FF_DIM/64, E_NUM), 256, 0, stream>>>(W2, W2t, FF_DIM, H_DIM);

  // GEMM1: mid = gelu(Xg @ W1[e] + b1[e]); BN=256: 16 col-blocks, NT=16
  gemm256p8_kernel<0,256><<<dim3(MAXT256*16), 512, 0, stream>>>(
      Xg, W1t, b1, mid, tiles256, ntiles256, cnt, offs, nullptr, FF_DIM, H_DIM, 4);
  // GEMM2: y = (mid @ W2[e] + b2[e]) * gate_w; BN=128: 8 col-blocks, NT=64
  gemm256p8_kernel<1,128><<<dim3(MAXT256*8), 512, 0, stream>>>(
      mid, W2t, b2, y, tiles256, ntiles256, cnt, offs, w_of, H_DIM, FF_DIM, 3);

  combine_kernel<<<T_TOK, 256, 0, stream>>>(y, slot_of, out);
}